// Round 1
// baseline (108.885 us; speedup 1.0000x reference)
//
#include <hip/hip_runtime.h>
#include <math.h>

#define BLOCK 256

// Per-thread 4x4 expm exploiting the zero last row:
//   A = [[M3x3, t],[0,0,0,0]]  =>  expm(A) = [[R, p],[0,0,0,1]], T[3][3]==1
// We carry only the top 3x4 block; the implicit last row is [0,0,0,1].
__global__ __launch_bounds__(BLOCK) void lie_expm_kernel(
    const float* __restrict__ in, float* __restrict__ out, int B)
{
    __shared__ float sh[BLOCK * 7];
    const int tid = threadIdx.x;
    const long long blockBase = (long long)blockIdx.x * BLOCK;

    // coalesced staging of (BLOCK,7) fp32 into LDS
    {
        const long long gbase = blockBase * 7;
        int valid = B - (int)blockBase;
        if (valid > BLOCK) valid = BLOCK;
        const int limit = valid * 7;
        for (int i = tid; i < BLOCK * 7; i += BLOCK)
            sh[i] = (i < limit) ? in[gbase + i] : 0.0f;
    }
    __syncthreads();

    const int b = (int)blockBase + tid;
    if (b >= B) return;

    const double v0 = (double)sh[tid * 7 + 0];
    const double v1 = (double)sh[tid * 7 + 1];
    const double v2 = (double)sh[tid * 7 + 2];
    const double v3 = (double)sh[tid * 7 + 3];
    const double v4 = (double)sh[tid * 7 + 4];
    const double v5 = (double)sh[tid * 7 + 5];
    const double v6 = (double)sh[tid * 7 + 6];

    // top 3 rows of A
    double X[3][4] = {
        {  v6, -v5,  v4, v0 },
        {  v5, -v6, -v3, v1 },
        { -v4,  v3, 0.0, v2 }
    };

    // inf-norm over the 3 live rows
    double n0 = fabs(X[0][0]) + fabs(X[0][1]) + fabs(X[0][2]) + fabs(X[0][3]);
    double n1 = fabs(X[1][0]) + fabs(X[1][1]) + fabs(X[1][2]) + fabs(X[1][3]);
    double n2 = fabs(X[2][0]) + fabs(X[2][1]) + fabs(X[2][2]) + fabs(X[2][3]);
    double nrm = fmax(n0, fmax(n1, n2));

    // scaling: pick s so nrm/2^s <= 0.5 (slightly conservative is fine)
    int s = 0;
    if (nrm > 0.5) s = ilogb(nrm) + 2;
    const double sc = ldexp(1.0, -s);
    #pragma unroll
    for (int i = 0; i < 3; i++)
        #pragma unroll
        for (int c = 0; c < 4; c++)
            X[i][c] *= sc;

    // Horner Taylor: P = I + X(I + X/2 (I + X/3 (...)))   N=13 terms
    double P[3][4] = { {1,0,0,0}, {0,1,0,0}, {0,0,1,0} };
    #pragma unroll
    for (int k = 13; k >= 1; k--) {
        double T[3][4];
        #pragma unroll
        for (int i = 0; i < 3; i++) {
            #pragma unroll
            for (int c = 0; c < 4; c++) {
                double acc = (c == 3) ? X[i][3] : 0.0; // X * implicit last row [0,0,0,1]
                acc = fma(X[i][0], P[0][c], acc);
                acc = fma(X[i][1], P[1][c], acc);
                acc = fma(X[i][2], P[2][c], acc);
                T[i][c] = acc;
            }
        }
        const double invk = 1.0 / (double)k; // constant-folded per unrolled iter
        #pragma unroll
        for (int i = 0; i < 3; i++)
            #pragma unroll
            for (int c = 0; c < 4; c++)
                P[i][c] = ((i == c) ? 1.0 : 0.0) + T[i][c] * invk;
    }

    // s squarings: P <- P_full * P_full  (implicit last row [0,0,0,1])
    for (int q = 0; q < s; q++) {
        double T[3][4];
        #pragma unroll
        for (int i = 0; i < 3; i++) {
            #pragma unroll
            for (int c = 0; c < 4; c++) {
                double acc = (c == 3) ? P[i][3] : 0.0;
                acc = fma(P[i][0], P[0][c], acc);
                acc = fma(P[i][1], P[1][c], acc);
                acc = fma(P[i][2], P[2][c], acc);
                T[i][c] = acc;
            }
        }
        #pragma unroll
        for (int i = 0; i < 3; i++)
            #pragma unroll
            for (int c = 0; c < 4; c++)
                P[i][c] = T[i][c];
    }

    // T[3][3] == 1 exactly => normalization is identity. Write out fp32.
    float4* o = (float4*)(out + (long long)b * 16);
    o[0] = make_float4((float)P[0][0], (float)P[0][1], (float)P[0][2], (float)P[0][3]);
    o[1] = make_float4((float)P[1][0], (float)P[1][1], (float)P[1][2], (float)P[1][3]);
    o[2] = make_float4((float)P[2][0], (float)P[2][1], (float)P[2][2], (float)P[2][3]);
    o[3] = make_float4(0.0f, 0.0f, 0.0f, 1.0f);
}

extern "C" void kernel_launch(void* const* d_in, const int* in_sizes, int n_in,
                              void* d_out, int out_size, void* d_ws, size_t ws_size,
                              hipStream_t stream) {
    const float* in = (const float*)d_in[0];
    float* out = (float*)d_out;
    const int B = in_sizes[0] / 7;
    const int grid = (B + BLOCK - 1) / BLOCK;
    lie_expm_kernel<<<grid, BLOCK, 0, stream>>>(in, out, B);
}

// Round 2
// 101.350 us; speedup vs baseline: 1.0743x; 1.0743x over previous
//
#include <hip/hip_runtime.h>
#include <math.h>

#define BLOCK 256

// Per-thread 4x4 expm exploiting the zero last row:
//   A = [[M3x3, t],[0,0,0,0]]  =>  expm(A) = [[R, p],[0,0,0,1]], T[3][3]==1
// Carry only the top 3x4 block; implicit last row [0,0,0,1].
// All math in fp32: tolerance is 1.77 absmax, fp32 path lands ~1e-3.
__global__ __launch_bounds__(BLOCK) void lie_expm_kernel(
    const float* __restrict__ in, float* __restrict__ out, int B)
{
    __shared__ float sh[BLOCK * 7];
    const int tid = threadIdx.x;
    const long long blockBase = (long long)blockIdx.x * BLOCK;

    // coalesced staging of (BLOCK,7) fp32 into LDS
    {
        const long long gbase = blockBase * 7;
        int valid = B - (int)blockBase;
        if (valid > BLOCK) valid = BLOCK;
        const int limit = valid * 7;
        for (int i = tid; i < BLOCK * 7; i += BLOCK)
            sh[i] = (i < limit) ? in[gbase + i] : 0.0f;
    }
    __syncthreads();

    const int b = (int)blockBase + tid;
    if (b >= B) return;

    const float v0 = sh[tid * 7 + 0];
    const float v1 = sh[tid * 7 + 1];
    const float v2 = sh[tid * 7 + 2];
    const float v3 = sh[tid * 7 + 3];
    const float v4 = sh[tid * 7 + 4];
    const float v5 = sh[tid * 7 + 5];
    const float v6 = sh[tid * 7 + 6];

    // top 3 rows of A
    float X[3][4] = {
        {  v6, -v5,  v4, v0 },
        {  v5, -v6, -v3, v1 },
        { -v4,  v3, 0.0f, v2 }
    };

    // inf-norm over the 3 live rows
    float n0 = fabsf(X[0][0]) + fabsf(X[0][1]) + fabsf(X[0][2]) + fabsf(X[0][3]);
    float n1 = fabsf(X[1][0]) + fabsf(X[1][1]) + fabsf(X[1][2]) + fabsf(X[1][3]);
    float n2 = fabsf(X[2][0]) + fabsf(X[2][1]) + fabsf(X[2][2]) + fabsf(X[2][3]);
    float nrm = fmaxf(n0, fmaxf(n1, n2));

    // scaling: pick s so nrm/2^s in [0.25, 0.5)
    int s = 0;
    if (nrm > 0.5f) s = ilogbf(nrm) + 2;
    const float sc = ldexpf(1.0f, -s);
    #pragma unroll
    for (int i = 0; i < 3; i++)
        #pragma unroll
        for (int c = 0; c < 4; c++)
            X[i][c] *= sc;

    // Horner Taylor: P = I + X(I + X/2 (I + X/3 (...)))   N=9 terms
    // remainder ~0.5^9/9! = 5.4e-9 relative -- below fp32 eps
    float P[3][4] = { {1,0,0,0}, {0,1,0,0}, {0,0,1,0} };
    #pragma unroll
    for (int k = 9; k >= 1; k--) {
        float T[3][4];
        #pragma unroll
        for (int i = 0; i < 3; i++) {
            #pragma unroll
            for (int c = 0; c < 4; c++) {
                float acc = (c == 3) ? X[i][3] : 0.0f; // X * implicit last row
                acc = fmaf(X[i][0], P[0][c], acc);
                acc = fmaf(X[i][1], P[1][c], acc);
                acc = fmaf(X[i][2], P[2][c], acc);
                T[i][c] = acc;
            }
        }
        const float invk = 1.0f / (float)k; // constant per unrolled iter
        #pragma unroll
        for (int i = 0; i < 3; i++)
            #pragma unroll
            for (int c = 0; c < 4; c++)
                P[i][c] = ((i == c) ? 1.0f : 0.0f) + T[i][c] * invk;
    }

    // s squarings: P <- P_full * P_full  (implicit last row [0,0,0,1])
    for (int q = 0; q < s; q++) {
        float T[3][4];
        #pragma unroll
        for (int i = 0; i < 3; i++) {
            #pragma unroll
            for (int c = 0; c < 4; c++) {
                float acc = (c == 3) ? P[i][3] : 0.0f;
                acc = fmaf(P[i][0], P[0][c], acc);
                acc = fmaf(P[i][1], P[1][c], acc);
                acc = fmaf(P[i][2], P[2][c], acc);
                T[i][c] = acc;
            }
        }
        #pragma unroll
        for (int i = 0; i < 3; i++)
            #pragma unroll
            for (int c = 0; c < 4; c++)
                P[i][c] = T[i][c];
    }

    // T[3][3] == 1 exactly => normalization is identity.
    float4* o = (float4*)(out + (long long)b * 16);
    o[0] = make_float4(P[0][0], P[0][1], P[0][2], P[0][3]);
    o[1] = make_float4(P[1][0], P[1][1], P[1][2], P[1][3]);
    o[2] = make_float4(P[2][0], P[2][1], P[2][2], P[2][3]);
    o[3] = make_float4(0.0f, 0.0f, 0.0f, 1.0f);
}

extern "C" void kernel_launch(void* const* d_in, const int* in_sizes, int n_in,
                              void* d_out, int out_size, void* d_ws, size_t ws_size,
                              hipStream_t stream) {
    const float* in = (const float*)d_in[0];
    float* out = (float*)d_out;
    const int B = in_sizes[0] / 7;
    const int grid = (B + BLOCK - 1) / BLOCK;
    lie_expm_kernel<<<grid, BLOCK, 0, stream>>>(in, out, B);
}